// Round 5
// baseline (4544.834 us; speedup 1.0000x reference)
//
#include <hip/hip_runtime.h>
#include <hip/hip_bf16.h>

typedef unsigned short u16;

#define NEG_INF (-__builtin_inff())

__device__ __forceinline__ u16 f2b(float f) {
  union { float f; unsigned u; } v;
  v.f = f;
  unsigned r = v.u + 0x7fff + ((v.u >> 16) & 1);  // RNE
  return (u16)(r >> 16);
}
__device__ __forceinline__ float b2f(u16 h) {
  union { float f; unsigned u; } v;
  v.u = ((unsigned)h) << 16;
  return v.f;
}

// ---- K1: kqv[b][h][s][f] = sum_e x[b][s][e]*Wkqv[h][e][f] + bkqv[h][f] ----
// one block per (b,h,s); 192 threads = one f each. K,Q,V stored bf16
// [bh][s][64] (f:0-63->K, 64-127->Q, 128-191->V).
__global__ __launch_bounds__(192) void kqv_naive(
    const float* __restrict__ x, const float* __restrict__ W,
    const float* __restrict__ bkqv, u16* __restrict__ Kb,
    u16* __restrict__ Qb, u16* __restrict__ Vb) {
  __shared__ float xr[1024];
  const int bid = blockIdx.x;      // bh*2048 + s
  const int s = bid & 2047;
  const int bh = bid >> 11;        // 0..31
  const int h = bh & 15;
  const int b = bh >> 4;
  const float* xrow = x + (size_t)(b * 2048 + s) * 1024;
  for (int i = threadIdx.x; i < 1024; i += 192) xr[i] = xrow[i];
  __syncthreads();
  const int f = threadIdx.x;  // 0..191
  const float* Wh = W + (size_t)h * 1024 * 192 + f;
  float acc = 0.f;
  for (int e = 0; e < 1024; e++) acc += xr[e] * Wh[(size_t)e * 192];
  acc += bkqv[h * 192 + f];
  const size_t base = ((size_t)bh * 2048 + s) * 64;
  if (f < 64)
    Kb[base + f] = f2b(acc);
  else if (f < 128)
    Qb[base + (f - 64)] = f2b(acc);
  else
    Vb[base + (f - 128)] = f2b(acc);
}

// ---- K2: naive causal attention row. one block per (bh, q); 256 threads ---
__global__ __launch_bounds__(256) void attn_naive(
    const u16* __restrict__ Kb, const u16* __restrict__ Qb,
    const u16* __restrict__ Vb, u16* __restrict__ SA) {
  __shared__ float sc[2048];
  __shared__ float red[256];
  __shared__ float qr[64];
  __shared__ float ps[4][64];
  const int bid = blockIdx.x;  // bh*2048 + q
  const int q = bid & 2047;
  const int bh = bid >> 11;
  const int t = threadIdx.x;
  const u16* Kh = Kb + (size_t)bh * 2048 * 64;
  const u16* Qr = Qb + ((size_t)bh * 2048 + q) * 64;
  const u16* Vh = Vb + (size_t)bh * 2048 * 64;
  if (t < 64) qr[t] = b2f(Qr[t]);
  __syncthreads();

  // scores (causal: k <= q), scaled by 1/8
  float lmax = NEG_INF;
  for (int k = t; k <= q; k += 256) {
    const u16* Kr = Kh + (size_t)k * 64;
    float d = 0.f;
    for (int e = 0; e < 64; e++) d += qr[e] * b2f(Kr[e]);
    d *= 0.125f;
    sc[k] = d;
    lmax = fmaxf(lmax, d);
  }
  red[t] = lmax;
  __syncthreads();
  for (int st = 128; st > 0; st >>= 1) {
    if (t < st) red[t] = fmaxf(red[t], red[t + st]);
    __syncthreads();
  }
  const float m = red[0];
  __syncthreads();

  // exp + sum
  float lsum = 0.f;
  for (int k = t; k <= q; k += 256) {
    float p = __expf(sc[k] - m);
    sc[k] = p;
    lsum += p;
  }
  red[t] = lsum;
  __syncthreads();
  for (int st = 128; st > 0; st >>= 1) {
    if (t < st) red[t] += red[t + st];
    __syncthreads();
  }
  const float l = red[0];

  // o[d] = sum_k p[k] * V[k][d]   (4 k-groups x 64 d)
  const int d = t & 63, g = t >> 6;
  float acc = 0.f;
  for (int k = g; k <= q; k += 4) acc += sc[k] * b2f(Vh[(size_t)k * 64 + d]);
  ps[g][d] = acc;
  __syncthreads();
  if (t < 64) {
    float o = (ps[0][t] + ps[1][t] + ps[2][t] + ps[3][t]) / l;
    const int hh = bh & 15, bb = bh >> 4;
    SA[((size_t)(bb * 2048 + q)) * 1024 + hh * 64 + t] = f2b(o);
  }
}

// ---- K3: out[ms][n] = sum_e SA[ms][e]*Wo[e][n] + bo[n] -- fp32 OUTPUT -----
// one block per ms=(b*2048+s); 256 threads x 4 n each.
__global__ __launch_bounds__(256) void out_naive(
    const u16* __restrict__ SA, const float* __restrict__ Wo,
    const float* __restrict__ bo, float* __restrict__ out) {
  __shared__ float row[1024];
  const int ms = blockIdx.x;  // 0..4095
  const u16* sr = SA + (size_t)ms * 1024;
  for (int i = threadIdx.x; i < 1024; i += 256) row[i] = b2f(sr[i]);
  __syncthreads();
  float acc[4] = {0.f, 0.f, 0.f, 0.f};
  for (int e = 0; e < 1024; e++) {
    const float xe = row[e];
    const float* wr = Wo + (size_t)e * 1024 + threadIdx.x;
#pragma unroll
    for (int j = 0; j < 4; j++) acc[j] += xe * wr[j * 256];
  }
#pragma unroll
  for (int j = 0; j < 4; j++) {
    const int n = threadIdx.x + j * 256;
    out[(size_t)ms * 1024 + n] = acc[j] + bo[n];
  }
}

extern "C" void kernel_launch(void* const* d_in, const int* in_sizes, int n_in,
                              void* d_out, int out_size, void* d_ws, size_t ws_size,
                              hipStream_t stream) {
  const float* x = (const float*)d_in[0];
  const float* Wkqv = (const float*)d_in[1];
  const float* bkqv = (const float*)d_in[2];
  const float* Wo = (const float*)d_in[3];
  const float* bo = (const float*)d_in[4];
  float* out = (float*)d_out;  // reference output dtype is float32

  char* w = (char*)d_ws;
  u16* Kb = (u16*)(w);                  // [32][2048][64] bf16  (8 MB)
  u16* Qb = (u16*)(w + 8388608);        // [32][2048][64] bf16  (8 MB)
  u16* Vb = (u16*)(w + 16777216);       // [32][2048][64] bf16  (8 MB)
  u16* SAb = (u16*)(w + 25165824);      // [B][S][E] bf16       (8 MB)

  kqv_naive<<<65536, 192, 0, stream>>>(x, Wkqv, bkqv, Kb, Qb, Vb);
  attn_naive<<<65536, 256, 0, stream>>>(Kb, Qb, Vb, SAb);
  out_naive<<<4096, 256, 0, stream>>>(SAb, Wo, bo, out);
}

// Round 6
// 237.326 us; speedup vs baseline: 19.1502x; 19.1502x over previous
//
#include <hip/hip_runtime.h>
#include <hip/hip_bf16.h>

typedef __attribute__((ext_vector_type(8))) short bf16x8;
typedef __attribute__((ext_vector_type(4))) float f32x4;
typedef unsigned short u16;

#define NEG_INF (-__builtin_inff())

// async global->LDS, 16B per lane. LDS dest must be wave-uniform (HW adds lane*16).
__device__ __forceinline__ void gload16(const void* g, void* l) {
  __builtin_amdgcn_global_load_lds(
      (const __attribute__((address_space(1))) void*)g,
      (__attribute__((address_space(3))) void*)l, 16, 0, 0);
}

__device__ __forceinline__ u16 f2b(float f) {
  union { float f; unsigned u; } v;
  v.f = f;
  unsigned r = v.u + 0x7fff + ((v.u >> 16) & 1);  // RNE
  return (u16)(r >> 16);
}

// ---------------- fp32 -> bf16 elementwise (x), 4 elems/thread -------------
__global__ __launch_bounds__(256) void cvt_f2b_kernel(
    const float* __restrict__ in, u16* __restrict__ out, int n4) {
  int i = blockIdx.x * 256 + threadIdx.x;
  if (i >= n4) return;
  float4 v = ((const float4*)in)[i];
  ushort2 a = {f2b(v.x), f2b(v.y)}, b = {f2b(v.z), f2b(v.w)};
  ((ushort2*)out)[i * 2] = a;
  ((ushort2*)out)[i * 2 + 1] = b;
}

// ------- batched transpose + cvt: dst[bz][c][r] = bf16(src[bz][r][c]) ------
__global__ __launch_bounds__(256) void transpose_f2b(
    const float* __restrict__ src, u16* __restrict__ dst, int R, int C) {
  __shared__ u16 t[32][33];
  int c0 = blockIdx.x * 32, r0 = blockIdx.y * 32;
  const float* s = src + (size_t)blockIdx.z * R * C;
  u16* d = dst + (size_t)blockIdx.z * R * C;
  for (int i = threadIdx.y; i < 32; i += 8)
    t[i][threadIdx.x] = f2b(s[(size_t)(r0 + i) * C + c0 + threadIdx.x]);
  __syncthreads();
  for (int i = threadIdx.y; i < 32; i += 8)
    d[(size_t)(c0 + i) * R + r0 + threadIdx.x] = t[threadIdx.x][i];
}

// ---------------- m97-style 128x128x32 bf16 GEMM mainloop ------------------
// A row-major [M][K] bf16, Bt row-major [N][K] bf16. 4 waves, each owns a
// 64x64 quadrant (4x4 frags of 16x16). acc: C[row=(lane>>4)*4+r][col=lane&15].
__device__ __forceinline__ void gemm_mainloop_128(
    const __hip_bfloat16* __restrict__ A, const __hip_bfloat16* __restrict__ Bt,
    int K, int m0, int n0, f32x4 acc[4][4], char* AsB, char* BsB) {
  const int tid = threadIdx.x;
  const int wave = tid >> 6, lane = tid & 63;
  const int lhi = lane >> 4, llo = lane & 15;
  const int wr = wave >> 1, wc = wave & 1;
  f32x4 z = {0.f, 0.f, 0.f, 0.f};
#pragma unroll
  for (int i = 0; i < 4; i++)
#pragma unroll
    for (int j = 0; j < 4; j++) acc[i][j] = z;

  for (int k0 = 0; k0 < K; k0 += 32) {
    __syncthreads();
#pragma unroll
    for (int i = 0; i < 2; i++) {
      int qb = i * 256 + wave * 64;  // wave-uniform chunk base
      int q = qb + lane;             // 16B chunk: row = q>>2, k8 = (q&3)*8
      gload16(A + ((size_t)(m0 + (q >> 2)) * K + k0 + (q & 3) * 8), AsB + qb * 16);
      gload16(Bt + ((size_t)(n0 + (q >> 2)) * K + k0 + (q & 3) * 8), BsB + qb * 16);
    }
    __syncthreads();
    bf16x8 a[4], b[4];
#pragma unroll
    for (int m4 = 0; m4 < 4; m4++)
      a[m4] = *(const bf16x8*)(AsB + (wr * 64 + m4 * 16 + llo) * 64 + lhi * 16);
#pragma unroll
    for (int n4 = 0; n4 < 4; n4++)
      b[n4] = *(const bf16x8*)(BsB + (wc * 64 + n4 * 16 + llo) * 64 + lhi * 16);
#pragma unroll
    for (int m4 = 0; m4 < 4; m4++)
#pragma unroll
      for (int n4 = 0; n4 < 4; n4++)
        acc[m4][n4] =
            __builtin_amdgcn_mfma_f32_16x16x32_bf16(a[m4], b[n4], acc[m4][n4], 0, 0, 0);
  }
}

// ------------- GEMM1: kqv = x @ WkqvT^T + bkqv, scatter to K/Q/Vt ----------
// n = h*192 + f ; f in [0,64)->K, [64,128)->Q (pre-scaled 1/8), [128,192)->Vt
// K,Q: [B][H][S][64] ; Vt: [B][H][64][S]
__global__ __launch_bounds__(256) void kqv_gemm(
    const __hip_bfloat16* __restrict__ x, const __hip_bfloat16* __restrict__ WT,
    const float* __restrict__ bkqv, __hip_bfloat16* __restrict__ Qb,
    __hip_bfloat16* __restrict__ Kb, __hip_bfloat16* __restrict__ Vt) {
  __shared__ __align__(16) __hip_bfloat16 As[128 * 32];
  __shared__ __align__(16) __hip_bfloat16 Bs[128 * 32];
  const int m0 = blockIdx.y * 128, n0 = blockIdx.x * 128;
  f32x4 acc[4][4];
  gemm_mainloop_128(x, WT, 1024, m0, n0, acc, (char*)As, (char*)Bs);

  const int tid = threadIdx.x, wave = tid >> 6, lane = tid & 63;
  const int lhi = lane >> 4, llo = lane & 15;
  const int wr = wave >> 1, wc = wave & 1;
#pragma unroll
  for (int m4 = 0; m4 < 4; m4++)
#pragma unroll
    for (int n4 = 0; n4 < 4; n4++)
#pragma unroll
      for (int r = 0; r < 4; r++) {
        int mg = m0 + wr * 64 + m4 * 16 + lhi * 4 + r;
        int ng = n0 + wc * 64 + n4 * 16 + llo;
        int b = mg >> 11, s = mg & 2047;
        int h = ng / 192, f = ng % 192;
        float v = acc[m4][n4][r] + bkqv[h * 192 + f];
        int chunk = f >> 6, d = f & 63;
        size_t bh = (size_t)(b * 16 + h);
        if (chunk == 0)
          Kb[(bh * 2048 + s) * 64 + d] = __float2bfloat16(v);
        else if (chunk == 1)
          Qb[(bh * 2048 + s) * 64 + d] = __float2bfloat16(v * 0.125f);
        else
          Vt[(bh * 64 + d) * 2048 + s] = __float2bfloat16(v);
      }
}

// ------------------- causal flash attention, D=64 --------------------------
// 1 block = one (b,h) and a 64-row q-tile; 4 waves x 16 q-rows; KB=32 keys.
__global__ __launch_bounds__(256) void attn_kernel(
    const __hip_bfloat16* __restrict__ Qb, const __hip_bfloat16* __restrict__ Kb,
    const __hip_bfloat16* __restrict__ Vt, __hip_bfloat16* __restrict__ SA) {
  __shared__ __align__(16) __hip_bfloat16 Ks[32 * 64];    // [key][d], swizzled
  __shared__ __align__(16) __hip_bfloat16 Vs[64 * 32];    // [d][key], swizzled
  __shared__ __align__(16) __hip_bfloat16 Ps[4][16 * 32]; // per-wave [q][key]
  const int bx = blockIdx.x;
  const int qt = 31 - (bx & 31);  // heavy tiles first
  const int bh = bx >> 5;
  const int b = bh >> 4, h = bh & 15;
  const int tid = threadIdx.x, wave = tid >> 6, lane = tid & 63;
  const int lhi = lane >> 4, llo = lane & 15;

  bf16x8 qf[2];  // Q rows (pre-scaled by 1/8): row=llo, d = lhi*8 (+0/+32)
  {
    const __hip_bfloat16* qsrc =
        Qb + ((size_t)bh * 2048 + qt * 64 + wave * 16 + llo) * 64 + lhi * 8;
    qf[0] = *(const bf16x8*)qsrc;
    qf[1] = *(const bf16x8*)(qsrc + 32);
  }
  f32x4 z = {0.f, 0.f, 0.f, 0.f};
  f32x4 o[4];
  float m_r[4], l_r[4];
#pragma unroll
  for (int i = 0; i < 4; i++) {
    o[i] = z;
    m_r[i] = NEG_INF;
    l_r[i] = 0.f;
  }

  const char* Kbase = (const char*)(Kb + (size_t)bh * 2048 * 64);
  const char* Vbase = (const char*)(Vt + (size_t)bh * 64 * 2048);
  char* KsB = (char*)Ks;
  char* VsB = (char*)Vs;
  char* PsB = (char*)(&Ps[wave][0]);
  const int nkt = 2 * (qt + 1);
  const int qg0 = qt * 64 + wave * 16 + lhi * 4;

  for (int kt = 0; kt < nkt; kt++) {
    const int k0 = kt * 32;
    __syncthreads();
    {
      const int q = tid;
      // K tile: 32 rows x 128B contiguous; src pre-swizzled so the swizzled
      // layout lands via the linear lane*16 LDS write.
      int soff = (q * 16) ^ (((q >> 3) & 7) << 4);
      gload16(Kbase + (size_t)k0 * 128 + soff, KsB + (wave * 64) * 16);
      // V tile: Vt rows (d) stride 2048 elems; 64B LDS rows.
      int d = q >> 2;
      int boff = ((q & 3) * 16) ^ (((d >> 1) & 3) << 4);
      gload16(Vbase + ((size_t)d * 2048 + k0) * 2 + boff, VsB + (wave * 64) * 16);
    }
    __syncthreads();

    // scores = (Q/8) . K^T   -> s0: keys k0+[0,16), s1: keys k0+[16,32)
    f32x4 s0 = z, s1 = z;
#pragma unroll
    for (int dblk = 0; dblk < 2; dblk++) {
      int pa0 = llo * 128 + dblk * 64 + lhi * 16;
      int pa1 = (16 + llo) * 128 + dblk * 64 + lhi * 16;
      bf16x8 bk0 = *(const bf16x8*)(KsB + (pa0 ^ ((llo & 7) << 4)));
      bf16x8 bk1 = *(const bf16x8*)(KsB + (pa1 ^ ((llo & 7) << 4)));
      s0 = __builtin_amdgcn_mfma_f32_16x16x32_bf16(qf[dblk], bk0, s0, 0, 0, 0);
      s1 = __builtin_amdgcn_mfma_f32_16x16x32_bf16(qf[dblk], bk1, s1, 0, 0, 0);
    }

    // online softmax (q-row = lhi*4+r, key col = llo / 16+llo)
#pragma unroll
    for (int r = 0; r < 4; r++) {
      const int qg = qg0 + r;
      float v0 = (k0 + llo <= qg) ? s0[r] : NEG_INF;
      float v1 = (k0 + 16 + llo <= qg) ? s1[r] : NEG_INF;
      float rm = fmaxf(v0, v1);
      rm = fmaxf(rm, __shfl_xor(rm, 1));
      rm = fmaxf(rm, __shfl_xor(rm, 2));
      rm = fmaxf(rm, __shfl_xor(rm, 4));
      rm = fmaxf(rm, __shfl_xor(rm, 8));
      float mn = fmaxf(m_r[r], rm);
      float sc = __expf(m_r[r] - mn);
      float p0 = __expf(v0 - mn);
      float p1 = __expf(v1 - mn);
      float rs = p0 + p1;
      rs += __shfl_xor(rs, 1);
      rs += __shfl_xor(rs, 2);
      rs += __shfl_xor(rs, 4);
      rs += __shfl_xor(rs, 8);
      l_r[r] = l_r[r] * sc + rs;
      m_r[r] = mn;
#pragma unroll
      for (int n4 = 0; n4 < 4; n4++) o[n4][r] *= sc;
      const int prow = lhi * 4 + r;
      const int sw = ((prow >> 1) & 3) << 4;
      *(__hip_bfloat16*)(PsB + ((prow * 64 + llo * 2) ^ sw)) = __float2bfloat16(p0);
      *(__hip_bfloat16*)(PsB + ((prow * 64 + 32 + llo * 2) ^ sw)) = __float2bfloat16(p1);
    }

    // o += P . V  (A: P[q=llo][k=lhi*8..]; B: Vs[d=n4*16+llo][k])
    bf16x8 ap = *(const bf16x8*)(PsB + ((llo * 64 + lhi * 16) ^ (((llo >> 1) & 3) << 4)));
#pragma unroll
    for (int n4 = 0; n4 < 4; n4++) {
      int d = n4 * 16 + llo;
      bf16x8 bv = *(const bf16x8*)(VsB + ((d * 64 + lhi * 16) ^ (((d >> 1) & 3) << 4)));
      o[n4] = __builtin_amdgcn_mfma_f32_16x16x32_bf16(ap, bv, o[n4], 0, 0, 0);
    }
  }

  // epilogue: SA[b][qg][h*64 + d] = o / l   (SA layout = [B][S][E])
#pragma unroll
  for (int r = 0; r < 4; r++) {
    float inv = 1.f / l_r[r];
    size_t ob = ((size_t)b * 2048 + qg0 + r) * 1024 + h * 64;
#pragma unroll
    for (int n4 = 0; n4 < 4; n4++)
      SA[ob + n4 * 16 + llo] = __float2bfloat16(o[n4][r] * inv);
  }
}

// ------------- GEMM3: out = SA @ Wo + bo  (fp32 OUTPUT) --------------------
__global__ __launch_bounds__(256) void out_gemm(
    const __hip_bfloat16* __restrict__ SA, const __hip_bfloat16* __restrict__ WoT,
    const float* __restrict__ bo, float* __restrict__ out) {
  __shared__ __align__(16) __hip_bfloat16 As[128 * 32];
  __shared__ __align__(16) __hip_bfloat16 Bs[128 * 32];
  const int m0 = blockIdx.y * 128, n0 = blockIdx.x * 128;
  f32x4 acc[4][4];
  gemm_mainloop_128(SA, WoT, 1024, m0, n0, acc, (char*)As, (char*)Bs);

  const int tid = threadIdx.x, wave = tid >> 6, lane = tid & 63;
  const int lhi = lane >> 4, llo = lane & 15;
  const int wr = wave >> 1, wc = wave & 1;
#pragma unroll
  for (int m4 = 0; m4 < 4; m4++)
#pragma unroll
    for (int n4 = 0; n4 < 4; n4++)
#pragma unroll
      for (int r = 0; r < 4; r++) {
        int mg = m0 + wr * 64 + m4 * 16 + lhi * 4 + r;
        int ng = n0 + wc * 64 + n4 * 16 + llo;
        out[(size_t)mg * 1024 + ng] = acc[m4][n4][r] + bo[ng];
      }
}

extern "C" void kernel_launch(void* const* d_in, const int* in_sizes, int n_in,
                              void* d_out, int out_size, void* d_ws, size_t ws_size,
                              hipStream_t stream) {
  const float* x = (const float*)d_in[0];
  const float* Wkqv = (const float*)d_in[1];
  const float* bkqv = (const float*)d_in[2];
  const float* Wo = (const float*)d_in[3];
  const float* bo = (const float*)d_in[4];
  float* out = (float*)d_out;  // fp32 output (verified R5)

  char* w = (char*)d_ws;
  __hip_bfloat16* WkqvT = (__hip_bfloat16*)(w);            // 3072x1024  (6 MB)
  __hip_bfloat16* WoT = (__hip_bfloat16*)(w + 6291456);    // 1024x1024  (2 MB)
  __hip_bfloat16* Qb = (__hip_bfloat16*)(w + 8388608);     // [B][H][S][64] (8 MB)
  __hip_bfloat16* Kb = (__hip_bfloat16*)(w + 16777216);    // [B][H][S][64] (8 MB)
  __hip_bfloat16* Vt = (__hip_bfloat16*)(w + 25165824);    // [B][H][64][S] (8 MB)
  __hip_bfloat16* SAb = (__hip_bfloat16*)(w + 33554432);   // [B][S][E]     (8 MB)
  __hip_bfloat16* xb = (__hip_bfloat16*)(w + 41943040);    // [B][S][E]     (8 MB)

  // x fp32 -> bf16
  cvt_f2b_kernel<<<4096, 256, 0, stream>>>(x, (u16*)xb, 1048576);
  // WkqvT[h*192+f][e] = bf16(Wkqv[h][e][f])
  transpose_f2b<<<dim3(6, 32, 16), dim3(32, 8, 1), 0, stream>>>(
      Wkqv, (u16*)WkqvT, 1024, 192);
  // WoT[n][k] = bf16(Wo[k][n])
  transpose_f2b<<<dim3(32, 32, 1), dim3(32, 8, 1), 0, stream>>>(
      Wo, (u16*)WoT, 1024, 1024);
  kqv_gemm<<<dim3(24, 32), 256, 0, stream>>>(xb, WkqvT, bkqv, Qb, Kb, Vt);
  attn_kernel<<<1024, 256, 0, stream>>>(Qb, Kb, Vt, SAb);
  out_gemm<<<dim3(8, 32), 256, 0, stream>>>(SAb, WoT, bo, out);
}

// Round 8
// 147.267 us; speedup vs baseline: 30.8613x; 1.6115x over previous
//
#include <hip/hip_runtime.h>
#include <hip/hip_bf16.h>

typedef __attribute__((ext_vector_type(8))) short bf16x8;
typedef __attribute__((ext_vector_type(4))) float f32x4;
typedef unsigned short u16;

#define NEG_INF (-__builtin_inff())

// async global->LDS, 16B per lane. LDS dest must be wave-uniform (HW adds lane*16).
__device__ __forceinline__ void gload16(const void* g, void* l) {
  __builtin_amdgcn_global_load_lds(
      (const __attribute__((address_space(1))) void*)g,
      (__attribute__((address_space(3))) void*)l, 16, 0, 0);
}

__device__ __forceinline__ u16 f2b(float f) {
  union { float f; unsigned u; } v;
  v.f = f;
  unsigned r = v.u + 0x7fff + ((v.u >> 16) & 1);  // RNE
  return (u16)(r >> 16);
}

// ---------------- fp32 -> bf16 elementwise (x), 4 elems/thread -------------
__global__ __launch_bounds__(256) void cvt_f2b_kernel(
    const float* __restrict__ in, u16* __restrict__ out, int n4) {
  int i = blockIdx.x * 256 + threadIdx.x;
  if (i >= n4) return;
  float4 v = ((const float4*)in)[i];
  ushort2 a = {f2b(v.x), f2b(v.y)}, b = {f2b(v.z), f2b(v.w)};
  ((ushort2*)out)[i * 2] = a;
  ((ushort2*)out)[i * 2 + 1] = b;
}

// ------- batched transpose + cvt: dst[bz][c][r] = bf16(src[bz][r][c]) ------
__global__ __launch_bounds__(256) void transpose_f2b(
    const float* __restrict__ src, u16* __restrict__ dst, int R, int C) {
  __shared__ u16 t[32][33];
  int c0 = blockIdx.x * 32, r0 = blockIdx.y * 32;
  const float* s = src + (size_t)blockIdx.z * R * C;
  u16* d = dst + (size_t)blockIdx.z * R * C;
  for (int i = threadIdx.y; i < 32; i += 8)
    t[i][threadIdx.x] = f2b(s[(size_t)(r0 + i) * C + c0 + threadIdx.x]);
  __syncthreads();
  for (int i = threadIdx.y; i < 32; i += 8)
    d[(size_t)(c0 + i) * R + r0 + threadIdx.x] = t[threadIdx.x][i];
}

// ---------------- m97-style 128x128x32 bf16 GEMM mainloop ------------------
__device__ __forceinline__ void gemm_mainloop_128(
    const __hip_bfloat16* __restrict__ A, const __hip_bfloat16* __restrict__ Bt,
    int K, int m0, int n0, f32x4 acc[4][4], char* AsB, char* BsB) {
  const int tid = threadIdx.x;
  const int wave = tid >> 6, lane = tid & 63;
  const int lhi = lane >> 4, llo = lane & 15;
  const int wr = wave >> 1, wc = wave & 1;
  f32x4 z = {0.f, 0.f, 0.f, 0.f};
#pragma unroll
  for (int i = 0; i < 4; i++)
#pragma unroll
    for (int j = 0; j < 4; j++) acc[i][j] = z;

  for (int k0 = 0; k0 < K; k0 += 32) {
    __syncthreads();
#pragma unroll
    for (int i = 0; i < 2; i++) {
      int qb = i * 256 + wave * 64;  // wave-uniform chunk base
      int q = qb + lane;             // 16B chunk: row = q>>2, k8 = (q&3)*8
      gload16(A + ((size_t)(m0 + (q >> 2)) * K + k0 + (q & 3) * 8), AsB + qb * 16);
      gload16(Bt + ((size_t)(n0 + (q >> 2)) * K + k0 + (q & 3) * 8), BsB + qb * 16);
    }
    __syncthreads();
    bf16x8 a[4], b[4];
#pragma unroll
    for (int m4 = 0; m4 < 4; m4++)
      a[m4] = *(const bf16x8*)(AsB + (wr * 64 + m4 * 16 + llo) * 64 + lhi * 16);
#pragma unroll
    for (int n4 = 0; n4 < 4; n4++)
      b[n4] = *(const bf16x8*)(BsB + (wc * 64 + n4 * 16 + llo) * 64 + lhi * 16);
#pragma unroll
    for (int m4 = 0; m4 < 4; m4++)
#pragma unroll
      for (int n4 = 0; n4 < 4; n4++)
        acc[m4][n4] =
            __builtin_amdgcn_mfma_f32_16x16x32_bf16(a[m4], b[n4], acc[m4][n4], 0, 0, 0);
  }
}

// ------------- GEMM1: kqv = x @ WkqvT^T + bkqv, scatter to K/Q/Vt ----------
__global__ __launch_bounds__(256) void kqv_gemm(
    const __hip_bfloat16* __restrict__ x, const __hip_bfloat16* __restrict__ WT,
    const float* __restrict__ bkqv, __hip_bfloat16* __restrict__ Qb,
    __hip_bfloat16* __restrict__ Kb, __hip_bfloat16* __restrict__ Vt) {
  __shared__ __align__(16) __hip_bfloat16 As[128 * 32];
  __shared__ __align__(16) __hip_bfloat16 Bs[128 * 32];
  const int m0 = blockIdx.y * 128, n0 = blockIdx.x * 128;
  f32x4 acc[4][4];
  gemm_mainloop_128(x, WT, 1024, m0, n0, acc, (char*)As, (char*)Bs);

  const int tid = threadIdx.x, wave = tid >> 6, lane = tid & 63;
  const int lhi = lane >> 4, llo = lane & 15;
  const int wr = wave >> 1, wc = wave & 1;
#pragma unroll
  for (int m4 = 0; m4 < 4; m4++)
#pragma unroll
    for (int n4 = 0; n4 < 4; n4++)
#pragma unroll
      for (int r = 0; r < 4; r++) {
        int mg = m0 + wr * 64 + m4 * 16 + lhi * 4 + r;
        int ng = n0 + wc * 64 + n4 * 16 + llo;
        int b = mg >> 11, s = mg & 2047;
        int h = ng / 192, f = ng % 192;
        float v = acc[m4][n4][r] + bkqv[h * 192 + f];
        int chunk = f >> 6, d = f & 63;
        size_t bh = (size_t)(b * 16 + h);
        if (chunk == 0)
          Kb[(bh * 2048 + s) * 64 + d] = __float2bfloat16(v);
        else if (chunk == 1)
          Qb[(bh * 2048 + s) * 64 + d] = __float2bfloat16(v * 0.125f);
        else
          Vt[(bh * 64 + d) * 2048 + s] = __float2bfloat16(v);
      }
}

// ------------------- causal flash attention, D=64 --------------------------
// 1 block = one (b,h) and a PAIR of 64-row q-tiles (qa=31-i, qb=i) -> exactly
// 33 KB=64 key-tiles per block (perfect balance). Double-buffered
// global_load_lds staging, counted vmcnt, raw s_barrier (no full drains).
__global__ __launch_bounds__(256) void attn_kernel(
    const __hip_bfloat16* __restrict__ Qb, const __hip_bfloat16* __restrict__ Kb,
    const __hip_bfloat16* __restrict__ Vt, __hip_bfloat16* __restrict__ SA) {
  __shared__ __align__(16) char lds[40960];  // Ks 2x8K | Vs 2x8K | Ps 4x2K
  const int bx0 = blockIdx.x;
  const int bx = (bx0 & 7) * 64 + (bx0 >> 3);  // XCD swizzle (512 % 8 == 0)
  const int bh = bx >> 4;
  const int ip = bx & 15;
  const int qa = 31 - ip, qbt = ip;   // heavy + light q-tile
  const int nta = qa + 1, nt = nta + qbt + 1;  // 33 tiles
  const int b = bh >> 4, h = bh & 15;
  const int tid = threadIdx.x, wave = tid >> 6, lane = tid & 63;
  const int lhi = lane >> 4, llo = lane & 15;

  // Q fragments for both passes (Q pre-scaled by 1/8 in kqv_gemm)
  const __hip_bfloat16* qpA =
      Qb + ((size_t)bh * 2048 + qa * 64 + wave * 16 + llo) * 64 + lhi * 8;
  const __hip_bfloat16* qpB =
      Qb + ((size_t)bh * 2048 + qbt * 64 + wave * 16 + llo) * 64 + lhi * 8;
  bf16x8 qA0 = *(const bf16x8*)qpA, qA1 = *(const bf16x8*)(qpA + 32);
  bf16x8 qB0 = *(const bf16x8*)qpB, qB1 = *(const bf16x8*)(qpB + 32);
  bf16x8 q0 = qA0, q1 = qA1;

  const char* Kg = (const char*)(Kb + (size_t)bh * 2048 * 64);
  const char* Vg = (const char*)(Vt + (size_t)bh * 64 * 2048);
  char* PsB = lds + 32768 + wave * 2048;

  f32x4 z = {0.f, 0.f, 0.f, 0.f};
  f32x4 o[4], l_p = z;
  float m_r[4];
#pragma unroll
  for (int i = 0; i < 4; i++) { o[i] = z; m_r[i] = NEG_INF; }
  int qg0 = qa * 64 + wave * 16 + lhi * 4;

  // ---- stage tile (k0 in keys) into buffer c (0/1): 4 gload16/thread ----
#define STAGE(c, k0)                                                          \
  {                                                                           \
    char* KsW = lds + (c)*8192;                                               \
    char* VsW = lds + 16384 + (c)*8192;                                       \
    _Pragma("unroll") for (int i = 0; i < 2; i++) {                           \
      int ch = i * 256 + tid;                                                 \
      int soff = (ch * 16) ^ (((ch >> 3) & 7) << 4);                          \
      gload16(Kg + (size_t)(k0)*128 + soff, KsW + (i * 256 + wave * 64) * 16);\
      int dd = ch >> 3, c8 = ch & 7;                                          \
      int boff = (c8 * 16) ^ ((dd & 7) << 4);                                 \
      gload16(Vg + (size_t)dd * 4096 + (size_t)(k0)*2 + boff,                 \
              VsW + (i * 256 + wave * 64) * 16);                              \
    }                                                                         \
  }

  STAGE(0, 0);
  int cur = 0;

  for (int T = 0; T < nt; T++) {
    const int Tn = T + 1;
    if (Tn < nt) {
      const int k0n = (Tn < nta ? Tn : Tn - nta) * 64;
      STAGE(cur ^ 1, k0n);
      asm volatile("s_waitcnt vmcnt(4)" ::: "memory");
    } else {
      asm volatile("s_waitcnt vmcnt(0)" ::: "memory");
    }
    __builtin_amdgcn_s_barrier();
    __builtin_amdgcn_sched_barrier(0);

    const int k0 = (T < nta ? T : T - nta) * 64;
    const bool masked = (T == nta - 1) || (T == nt - 1);
    const char* KsB = lds + cur * 8192;
    const char* VsB = lds + 16384 + cur * 8192;

    // ---- QK^T: s[j][r] = score(q=qg0+r, key=k0+j*16+llo) ----
    f32x4 s[4] = {z, z, z, z};
#pragma unroll
    for (int j = 0; j < 4; j++) {
      const int row = j * 16 + llo;
      const int rx = (row & 7) << 4;
      bf16x8 bk0 = *(const bf16x8*)(KsB + ((row * 128 + lhi * 16) ^ rx));
      bf16x8 bk1 = *(const bf16x8*)(KsB + ((row * 128 + 64 + lhi * 16) ^ rx));
      s[j] = __builtin_amdgcn_mfma_f32_16x16x32_bf16(q0, bk0, s[j], 0, 0, 0);
      s[j] = __builtin_amdgcn_mfma_f32_16x16x32_bf16(q1, bk1, s[j], 0, 0, 0);
    }

    // ---- online softmax (row-max shfl-reduced; l kept as per-lane partial)
#pragma unroll
    for (int r = 0; r < 4; r++) {
      float v0, v1, v2, v3;
      if (masked) {
        const int qg = qg0 + r;
        v0 = (k0 + llo <= qg) ? s[0][r] : NEG_INF;
        v1 = (k0 + 16 + llo <= qg) ? s[1][r] : NEG_INF;
        v2 = (k0 + 32 + llo <= qg) ? s[2][r] : NEG_INF;
        v3 = (k0 + 48 + llo <= qg) ? s[3][r] : NEG_INF;
      } else {
        v0 = s[0][r]; v1 = s[1][r]; v2 = s[2][r]; v3 = s[3][r];
      }
      float rm = fmaxf(fmaxf(v0, v1), fmaxf(v2, v3));
      rm = fmaxf(rm, __shfl_xor(rm, 1));
      rm = fmaxf(rm, __shfl_xor(rm, 2));
      rm = fmaxf(rm, __shfl_xor(rm, 4));
      rm = fmaxf(rm, __shfl_xor(rm, 8));
      const float mn = fmaxf(m_r[r], rm);
      const float sc = __expf(m_r[r] - mn);
      m_r[r] = mn;
      const float p0 = __expf(v0 - mn), p1 = __expf(v1 - mn);
      const float p2 = __expf(v2 - mn), p3 = __expf(v3 - mn);
      l_p[r] = l_p[r] * sc + ((p0 + p1) + (p2 + p3));
#pragma unroll
      for (int n4 = 0; n4 < 4; n4++) o[n4][r] *= sc;
      const int prow = lhi * 4 + r;
      const int px = (prow & 7) << 4;
      *(__hip_bfloat16*)(PsB + ((prow * 128 + llo * 2) ^ px)) = __float2bfloat16(p0);
      *(__hip_bfloat16*)(PsB + ((prow * 128 + 32 + llo * 2) ^ px)) = __float2bfloat16(p1);
      *(__hip_bfloat16*)(PsB + ((prow * 128 + 64 + llo * 2) ^ px)) = __float2bfloat16(p2);
      *(__hip_bfloat16*)(PsB + ((prow * 128 + 96 + llo * 2) ^ px)) = __float2bfloat16(p3);
    }

    // ---- PV: o[n4] += P(16x64) . V^T(64x16-block) ----
    {
      const int qx = (llo & 7) << 4;
      bf16x8 ap0 = *(const bf16x8*)(PsB + ((llo * 128 + lhi * 16) ^ qx));
      bf16x8 ap1 = *(const bf16x8*)(PsB + ((llo * 128 + 64 + lhi * 16) ^ qx));
#pragma unroll
      for (int n4 = 0; n4 < 4; n4++) {
        const int d = n4 * 16 + llo;
        const int dx = (d & 7) << 4;
        bf16x8 bv0 = *(const bf16x8*)(VsB + ((d * 128 + lhi * 16) ^ dx));
        bf16x8 bv1 = *(const bf16x8*)(VsB + ((d * 128 + 64 + lhi * 16) ^ dx));
        o[n4] = __builtin_amdgcn_mfma_f32_16x16x32_bf16(ap0, bv0, o[n4], 0, 0, 0);
        o[n4] = __builtin_amdgcn_mfma_f32_16x16x32_bf16(ap1, bv1, o[n4], 0, 0, 0);
      }
    }
    __builtin_amdgcn_sched_barrier(0);
    __builtin_amdgcn_s_barrier();  // all waves done reading buf[cur]

    if (T == nta - 1) {  // pass A epilogue + reset for pass B
      // 1) write ALL rows first (o[n4][r] must stay intact until done)
#pragma unroll
      for (int r = 0; r < 4; r++) {
        float l = l_p[r];
        l += __shfl_xor(l, 1); l += __shfl_xor(l, 2);
        l += __shfl_xor(l, 4); l += __shfl_xor(l, 8);
        const float inv = 1.f / l;
        const size_t ob = ((size_t)b * 2048 + qg0 + r) * 1024 + h * 64;
#pragma unroll
        for (int n4 = 0; n4 < 4; n4++)
          SA[ob + n4 * 16 + llo] = __float2bfloat16(o[n4][r] * inv);
      }
      // 2) then reset state for pass B
#pragma unroll
      for (int i = 0; i < 4; i++) { o[i] = z; m_r[i] = NEG_INF; }
      l_p = z;
      q0 = qB0; q1 = qB1;
      qg0 = qbt * 64 + wave * 16 + lhi * 4;
    }
    cur ^= 1;
  }

  // pass B epilogue
#pragma unroll
  for (int r = 0; r < 4; r++) {
    float l = l_p[r];
    l += __shfl_xor(l, 1); l += __shfl_xor(l, 2);
    l += __shfl_xor(l, 4); l += __shfl_xor(l, 8);
    const float inv = 1.f / l;
    const size_t ob = ((size_t)b * 2048 + qg0 + r) * 1024 + h * 64;
#pragma unroll
    for (int n4 = 0; n4 < 4; n4++)
      SA[ob + n4 * 16 + llo] = __float2bfloat16(o[n4][r] * inv);
  }
#undef STAGE
}

// ------------- GEMM3: out = SA @ Wo + bo  (fp32 OUTPUT) --------------------
__global__ __launch_bounds__(256) void out_gemm(
    const __hip_bfloat16* __restrict__ SA, const __hip_bfloat16* __restrict__ WoT,
    const float* __restrict__ bo, float* __restrict__ out) {
  __shared__ __align__(16) __hip_bfloat16 As[128 * 32];
  __shared__ __align__(16) __hip_bfloat16 Bs[128 * 32];
  const int m0 = blockIdx.y * 128, n0 = blockIdx.x * 128;
  f32x4 acc[4][4];
  gemm_mainloop_128(SA, WoT, 1024, m0, n0, acc, (char*)As, (char*)Bs);

  const int tid = threadIdx.x, wave = tid >> 6, lane = tid & 63;
  const int lhi = lane >> 4, llo = lane & 15;
  const int wr = wave >> 1, wc = wave & 1;
#pragma unroll
  for (int m4 = 0; m4 < 4; m4++)
#pragma unroll
    for (int n4 = 0; n4 < 4; n4++)
#pragma unroll
      for (int r = 0; r < 4; r++) {
        int mg = m0 + wr * 64 + m4 * 16 + lhi * 4 + r;
        int ng = n0 + wc * 64 + n4 * 16 + llo;
        out[(size_t)mg * 1024 + ng] = acc[m4][n4][r] + bo[ng];
      }
}

extern "C" void kernel_launch(void* const* d_in, const int* in_sizes, int n_in,
                              void* d_out, int out_size, void* d_ws, size_t ws_size,
                              hipStream_t stream) {
  const float* x = (const float*)d_in[0];
  const float* Wkqv = (const float*)d_in[1];
  const float* bkqv = (const float*)d_in[2];
  const float* Wo = (const float*)d_in[3];
  const float* bo = (const float*)d_in[4];
  float* out = (float*)d_out;  // fp32 output (verified R5)

  char* w = (char*)d_ws;
  __hip_bfloat16* WkqvT = (__hip_bfloat16*)(w);            // 3072x1024  (6 MB)
  __hip_bfloat16* WoT = (__hip_bfloat16*)(w + 6291456);    // 1024x1024  (2 MB)
  __hip_bfloat16* Qb = (__hip_bfloat16*)(w + 8388608);     // [B][H][S][64] (8 MB)
  __hip_bfloat16* Kb = (__hip_bfloat16*)(w + 16777216);    // [B][H][S][64] (8 MB)
  __hip_bfloat16* Vt = (__hip_bfloat16*)(w + 25165824);    // [B][H][64][S] (8 MB)
  __hip_bfloat16* SAb = (__hip_bfloat16*)(w + 33554432);   // [B][S][E]     (8 MB)
  __hip_bfloat16* xb = (__hip_bfloat16*)(w + 41943040);    // [B][S][E]     (8 MB)

  cvt_f2b_kernel<<<4096, 256, 0, stream>>>(x, (u16*)xb, 1048576);
  transpose_f2b<<<dim3(6, 32, 16), dim3(32, 8, 1), 0, stream>>>(
      Wkqv, (u16*)WkqvT, 1024, 192);
  transpose_f2b<<<dim3(32, 32, 1), dim3(32, 8, 1), 0, stream>>>(
      Wo, (u16*)WoT, 1024, 1024);
  kqv_gemm<<<dim3(24, 32), 256, 0, stream>>>(xb, WkqvT, bkqv, Qb, Kb, Vt);
  attn_kernel<<<512, 256, 0, stream>>>(Qb, Kb, Vt, SAb);
  out_gemm<<<dim3(8, 32), 256, 0, stream>>>(SAb, WoT, bo, out);
}

// Round 9
// 129.126 us; speedup vs baseline: 35.1969x; 1.1405x over previous
//
#include <hip/hip_runtime.h>
#include <hip/hip_bf16.h>

typedef __attribute__((ext_vector_type(8))) short bf16x8;
typedef __attribute__((ext_vector_type(4))) float f32x4;
typedef unsigned short u16;

#define NEG_INF (-__builtin_inff())

// async global->LDS, 16B per lane. LDS dest must be wave-uniform (HW adds lane*16).
__device__ __forceinline__ void gload16(const void* g, void* l) {
  __builtin_amdgcn_global_load_lds(
      (const __attribute__((address_space(1))) void*)g,
      (__attribute__((address_space(3))) void*)l, 16, 0, 0);
}

__device__ __forceinline__ u16 f2b(float f) {
  union { float f; unsigned u; } v;
  v.f = f;
  unsigned r = v.u + 0x7fff + ((v.u >> 16) & 1);  // RNE
  return (u16)(r >> 16);
}

// ---------------- fp32 -> bf16 elementwise (x), 4 elems/thread -------------
__global__ __launch_bounds__(256) void cvt_f2b_kernel(
    const float* __restrict__ in, u16* __restrict__ out, int n4) {
  int i = blockIdx.x * 256 + threadIdx.x;
  if (i >= n4) return;
  float4 v = ((const float4*)in)[i];
  ushort2 a = {f2b(v.x), f2b(v.y)}, b = {f2b(v.z), f2b(v.w)};
  ((ushort2*)out)[i * 2] = a;
  ((ushort2*)out)[i * 2 + 1] = b;
}

// ------- batched transpose + cvt: dst[bz][c][r] = bf16(src[bz][r][c]) ------
__global__ __launch_bounds__(256) void transpose_f2b(
    const float* __restrict__ src, u16* __restrict__ dst, int R, int C) {
  __shared__ u16 t[32][33];
  int c0 = blockIdx.x * 32, r0 = blockIdx.y * 32;
  const float* s = src + (size_t)blockIdx.z * R * C;
  u16* d = dst + (size_t)blockIdx.z * R * C;
  for (int i = threadIdx.y; i < 32; i += 8)
    t[i][threadIdx.x] = f2b(s[(size_t)(r0 + i) * C + c0 + threadIdx.x]);
  __syncthreads();
  for (int i = threadIdx.y; i < 32; i += 8)
    d[(size_t)(c0 + i) * R + r0 + threadIdx.x] = t[threadIdx.x][i];
}

// ---------------- m97-style 128x128x32 bf16 GEMM mainloop ------------------
__device__ __forceinline__ void gemm_mainloop_128(
    const __hip_bfloat16* __restrict__ A, const __hip_bfloat16* __restrict__ Bt,
    int K, int m0, int n0, f32x4 acc[4][4], char* AsB, char* BsB) {
  const int tid = threadIdx.x;
  const int wave = tid >> 6, lane = tid & 63;
  const int lhi = lane >> 4, llo = lane & 15;
  const int wr = wave >> 1, wc = wave & 1;
  f32x4 z = {0.f, 0.f, 0.f, 0.f};
#pragma unroll
  for (int i = 0; i < 4; i++)
#pragma unroll
    for (int j = 0; j < 4; j++) acc[i][j] = z;

  for (int k0 = 0; k0 < K; k0 += 32) {
    __syncthreads();
#pragma unroll
    for (int i = 0; i < 2; i++) {
      int qb = i * 256 + wave * 64;  // wave-uniform chunk base
      int q = qb + lane;             // 16B chunk: row = q>>2, k8 = (q&3)*8
      gload16(A + ((size_t)(m0 + (q >> 2)) * K + k0 + (q & 3) * 8), AsB + qb * 16);
      gload16(Bt + ((size_t)(n0 + (q >> 2)) * K + k0 + (q & 3) * 8), BsB + qb * 16);
    }
    __syncthreads();
    bf16x8 a[4], b[4];
#pragma unroll
    for (int m4 = 0; m4 < 4; m4++)
      a[m4] = *(const bf16x8*)(AsB + (wr * 64 + m4 * 16 + llo) * 64 + lhi * 16);
#pragma unroll
    for (int n4 = 0; n4 < 4; n4++)
      b[n4] = *(const bf16x8*)(BsB + (wc * 64 + n4 * 16 + llo) * 64 + lhi * 16);
#pragma unroll
    for (int m4 = 0; m4 < 4; m4++)
#pragma unroll
      for (int n4 = 0; n4 < 4; n4++)
        acc[m4][n4] =
            __builtin_amdgcn_mfma_f32_16x16x32_bf16(a[m4], b[n4], acc[m4][n4], 0, 0, 0);
  }
}

// ------------- GEMM1: kqv = x @ WkqvT^T + bkqv, scatter to K/Q/Vt ----------
// Q pre-scaled by 0.125 * log2(e) (attn works in exp2 domain).
__global__ __launch_bounds__(256) void kqv_gemm(
    const __hip_bfloat16* __restrict__ x, const __hip_bfloat16* __restrict__ WT,
    const float* __restrict__ bkqv, __hip_bfloat16* __restrict__ Qb,
    __hip_bfloat16* __restrict__ Kb, __hip_bfloat16* __restrict__ Vt) {
  __shared__ __align__(16) __hip_bfloat16 As[128 * 32];
  __shared__ __align__(16) __hip_bfloat16 Bs[128 * 32];
  const int m0 = blockIdx.y * 128, n0 = blockIdx.x * 128;
  f32x4 acc[4][4];
  gemm_mainloop_128(x, WT, 1024, m0, n0, acc, (char*)As, (char*)Bs);

  const int tid = threadIdx.x, wave = tid >> 6, lane = tid & 63;
  const int lhi = lane >> 4, llo = lane & 15;
  const int wr = wave >> 1, wc = wave & 1;
#pragma unroll
  for (int m4 = 0; m4 < 4; m4++)
#pragma unroll
    for (int n4 = 0; n4 < 4; n4++)
#pragma unroll
      for (int r = 0; r < 4; r++) {
        int mg = m0 + wr * 64 + m4 * 16 + lhi * 4 + r;
        int ng = n0 + wc * 64 + n4 * 16 + llo;
        int b = mg >> 11, s = mg & 2047;
        int h = ng / 192, f = ng % 192;
        float v = acc[m4][n4][r] + bkqv[h * 192 + f];
        int chunk = f >> 6, d = f & 63;
        size_t bh = (size_t)(b * 16 + h);
        if (chunk == 0)
          Kb[(bh * 2048 + s) * 64 + d] = __float2bfloat16(v);
        else if (chunk == 1)
          Qb[(bh * 2048 + s) * 64 + d] = __float2bfloat16(v * 0.180336880f);
        else
          Vt[(bh * 64 + d) * 2048 + s] = __float2bfloat16(v);
      }
}

// ------------------- causal flash attention, D=64 --------------------------
// 1 block = one (b,h) and a PAIR of 64-row q-tiles (qa=31-i, qb=i) -> 33
// KB=64 key-tiles per block. Swapped QK^T (mfma(K,Q)): each lane owns q=llo
// with 16 local scores -> scalar m/l state, 2-shfl row reduce, packed b64
// P-writes, defer-max rescale (THR=5 in log2 units), exp2 softmax.
__global__ __launch_bounds__(256) void attn_kernel(
    const __hip_bfloat16* __restrict__ Qb, const __hip_bfloat16* __restrict__ Kb,
    const __hip_bfloat16* __restrict__ Vt, __hip_bfloat16* __restrict__ SA) {
  __shared__ __align__(16) char lds[40960];  // Ks 2x8K | Vs 2x8K | Ps 4x2K
  const int bx0 = blockIdx.x;
  const int bx = (bx0 & 7) * 64 + (bx0 >> 3);  // XCD swizzle (512 % 8 == 0)
  const int bh = bx >> 4;
  const int ip = bx & 15;
  const int qa = 31 - ip, qbt = ip;   // heavy + light q-tile
  const int nta = qa + 1, nt = nta + qbt + 1;  // 33 tiles
  const int b = bh >> 4, h = bh & 15;
  const int tid = threadIdx.x, wave = tid >> 6, lane = tid & 63;
  const int lhi = lane >> 4, llo = lane & 15;
  const int lhi4 = lhi * 4;

  // Q fragments for both passes (Q pre-scaled by 0.125*log2e in kqv_gemm)
  const __hip_bfloat16* qpA =
      Qb + ((size_t)bh * 2048 + qa * 64 + wave * 16 + llo) * 64 + lhi * 8;
  const __hip_bfloat16* qpB =
      Qb + ((size_t)bh * 2048 + qbt * 64 + wave * 16 + llo) * 64 + lhi * 8;
  bf16x8 qA0 = *(const bf16x8*)qpA, qA1 = *(const bf16x8*)(qpA + 32);
  bf16x8 qB0 = *(const bf16x8*)qpB, qB1 = *(const bf16x8*)(qpB + 32);
  bf16x8 q0 = qA0, q1 = qA1;

  const char* Kg = (const char*)(Kb + (size_t)bh * 2048 * 64);
  const char* Vg = (const char*)(Vt + (size_t)bh * 64 * 2048);
  char* PsB = lds + 32768 + wave * 2048;

  f32x4 z = {0.f, 0.f, 0.f, 0.f};
  f32x4 o[4];
  float m_s = NEG_INF, l_s = 0.f;
#pragma unroll
  for (int i = 0; i < 4; i++) o[i] = z;
  int qg = qa * 64 + wave * 16 + llo;     // masking row (this lane's q)
  int qg0 = qa * 64 + wave * 16 + lhi4;   // output row base (PV layout)

  // ---- stage tile (k0 in keys) into buffer c (0/1): 4 gload16/thread ----
#define STAGE(c, k0)                                                          \
  {                                                                           \
    char* KsW = lds + (c)*8192;                                               \
    char* VsW = lds + 16384 + (c)*8192;                                       \
    _Pragma("unroll") for (int i = 0; i < 2; i++) {                           \
      int ch = i * 256 + tid;                                                 \
      int soff = (ch * 16) ^ (((ch >> 3) & 7) << 4);                          \
      gload16(Kg + (size_t)(k0)*128 + soff, KsW + (i * 256 + wave * 64) * 16);\
      int dd = ch >> 3, c8 = ch & 7;                                          \
      int boff = (c8 * 16) ^ ((dd & 7) << 4);                                 \
      gload16(Vg + (size_t)dd * 4096 + (size_t)(k0)*2 + boff,                 \
              VsW + (i * 256 + wave * 64) * 16);                              \
    }                                                                         \
  }

  STAGE(0, 0);
  int cur = 0;

  for (int T = 0; T < nt; T++) {
    const int Tn = T + 1;
    if (Tn < nt) {
      const int k0n = (Tn < nta ? Tn : Tn - nta) * 64;
      STAGE(cur ^ 1, k0n);
      asm volatile("s_waitcnt vmcnt(4)" ::: "memory");
    } else {
      asm volatile("s_waitcnt vmcnt(0)" ::: "memory");
    }
    __builtin_amdgcn_s_barrier();
    __builtin_amdgcn_sched_barrier(0);

    const int k0 = (T < nta ? T : T - nta) * 64;
    const bool masked = (T == nta - 1) || (T == nt - 1);
    const char* KsB = lds + cur * 8192;
    const char* VsB = lds + 16384 + cur * 8192;

    // ---- QK^T swapped: s[j] = C[key=j*16+lhi4+r][q=llo] ----
    f32x4 s[4] = {z, z, z, z};
#pragma unroll
    for (int j = 0; j < 4; j++) {
      const int row = j * 16 + llo;
      const int rx = (row & 7) << 4;
      bf16x8 bk0 = *(const bf16x8*)(KsB + ((row * 128 + lhi * 16) ^ rx));
      bf16x8 bk1 = *(const bf16x8*)(KsB + ((row * 128 + 64 + lhi * 16) ^ rx));
      s[j] = __builtin_amdgcn_mfma_f32_16x16x32_bf16(bk0, q0, s[j], 0, 0, 0);
      s[j] = __builtin_amdgcn_mfma_f32_16x16x32_bf16(bk1, q1, s[j], 0, 0, 0);
    }

    // ---- in-lane online softmax (lane owns q=llo; 16 scores local) ----
    if (masked) {
#pragma unroll
      for (int j = 0; j < 4; j++)
#pragma unroll
        for (int r = 0; r < 4; r++)
          if (k0 + j * 16 + lhi4 + r > qg) s[j][r] = NEG_INF;
    }
    float pmax = s[0][0];
#pragma unroll
    for (int j = 0; j < 4; j++)
#pragma unroll
      for (int r = 0; r < 4; r++) pmax = fmaxf(pmax, s[j][r]);
    pmax = fmaxf(pmax, __shfl_xor(pmax, 16));
    pmax = fmaxf(pmax, __shfl_xor(pmax, 32));
    if (!__all(pmax - m_s <= 5.0f)) {  // defer-max: rescale rarely
      const float mn = fmaxf(m_s, pmax);
      const float sc = __builtin_exp2f(m_s - mn);
      m_s = mn;
      l_s *= sc;
#pragma unroll
      for (int r = 0; r < 4; r++) {
        const float scr = __shfl(sc, lhi4 + r);
#pragma unroll
        for (int n4 = 0; n4 < 4; n4++) o[n4][r] *= scr;
      }
    }
    const int px = (llo & 7) << 4;
    float ps = 0.f;
#pragma unroll
    for (int j = 0; j < 4; j++) {
      ushort4 pw;
#pragma unroll
      for (int r = 0; r < 4; r++) {
        const float p = __builtin_exp2f(s[j][r] - m_s);
        ps += p;
        ((__hip_bfloat16*)&pw)[r] = __float2bfloat16(p);
      }
      *(ushort4*)(PsB + ((llo * 128 + j * 32 + lhi * 8) ^ px)) = pw;
    }
    l_s += ps;

    // ---- PV: o[n4] += P(16x64) . V^T ----
    {
      bf16x8 ap0 = *(const bf16x8*)(PsB + ((llo * 128 + lhi * 16) ^ px));
      bf16x8 ap1 = *(const bf16x8*)(PsB + ((llo * 128 + 64 + lhi * 16) ^ px));
#pragma unroll
      for (int n4 = 0; n4 < 4; n4++) {
        const int d = n4 * 16 + llo;
        const int dx = (d & 7) << 4;
        bf16x8 bv0 = *(const bf16x8*)(VsB + ((d * 128 + lhi * 16) ^ dx));
        bf16x8 bv1 = *(const bf16x8*)(VsB + ((d * 128 + 64 + lhi * 16) ^ dx));
        o[n4] = __builtin_amdgcn_mfma_f32_16x16x32_bf16(ap0, bv0, o[n4], 0, 0, 0);
        o[n4] = __builtin_amdgcn_mfma_f32_16x16x32_bf16(ap1, bv1, o[n4], 0, 0, 0);
      }
    }
    __builtin_amdgcn_sched_barrier(0);
    __builtin_amdgcn_s_barrier();  // all waves done reading buf[cur]

    if (T == nta - 1) {  // pass A epilogue + reset for pass B
      float l = l_s;
      l += __shfl_xor(l, 16);
      l += __shfl_xor(l, 32);
      const float inv = 1.f / l;
#pragma unroll
      for (int r = 0; r < 4; r++) {
        const float invr = __shfl(inv, lhi4 + r);
        const size_t ob = ((size_t)b * 2048 + qg0 + r) * 1024 + h * 64;
#pragma unroll
        for (int n4 = 0; n4 < 4; n4++)
          SA[ob + n4 * 16 + llo] = __float2bfloat16(o[n4][r] * invr);
      }
#pragma unroll
      for (int i = 0; i < 4; i++) o[i] = z;
      m_s = NEG_INF;
      l_s = 0.f;
      q0 = qB0; q1 = qB1;
      qg = qbt * 64 + wave * 16 + llo;
      qg0 = qbt * 64 + wave * 16 + lhi4;
    }
    cur ^= 1;
  }

  // pass B epilogue
  {
    float l = l_s;
    l += __shfl_xor(l, 16);
    l += __shfl_xor(l, 32);
    const float inv = 1.f / l;
#pragma unroll
    for (int r = 0; r < 4; r++) {
      const float invr = __shfl(inv, lhi4 + r);
      const size_t ob = ((size_t)b * 2048 + qg0 + r) * 1024 + h * 64;
#pragma unroll
      for (int n4 = 0; n4 < 4; n4++)
        SA[ob + n4 * 16 + llo] = __float2bfloat16(o[n4][r] * invr);
    }
  }
#undef STAGE
}

// ------------- GEMM3: out = SA @ Wo + bo  (fp32 OUTPUT) --------------------
__global__ __launch_bounds__(256) void out_gemm(
    const __hip_bfloat16* __restrict__ SA, const __hip_bfloat16* __restrict__ WoT,
    const float* __restrict__ bo, float* __restrict__ out) {
  __shared__ __align__(16) __hip_bfloat16 As[128 * 32];
  __shared__ __align__(16) __hip_bfloat16 Bs[128 * 32];
  const int m0 = blockIdx.y * 128, n0 = blockIdx.x * 128;
  f32x4 acc[4][4];
  gemm_mainloop_128(SA, WoT, 1024, m0, n0, acc, (char*)As, (char*)Bs);

  const int tid = threadIdx.x, wave = tid >> 6, lane = tid & 63;
  const int lhi = lane >> 4, llo = lane & 15;
  const int wr = wave >> 1, wc = wave & 1;
#pragma unroll
  for (int m4 = 0; m4 < 4; m4++)
#pragma unroll
    for (int n4 = 0; n4 < 4; n4++)
#pragma unroll
      for (int r = 0; r < 4; r++) {
        int mg = m0 + wr * 64 + m4 * 16 + lhi * 4 + r;
        int ng = n0 + wc * 64 + n4 * 16 + llo;
        out[(size_t)mg * 1024 + ng] = acc[m4][n4][r] + bo[ng];
      }
}

extern "C" void kernel_launch(void* const* d_in, const int* in_sizes, int n_in,
                              void* d_out, int out_size, void* d_ws, size_t ws_size,
                              hipStream_t stream) {
  const float* x = (const float*)d_in[0];
  const float* Wkqv = (const float*)d_in[1];
  const float* bkqv = (const float*)d_in[2];
  const float* Wo = (const float*)d_in[3];
  const float* bo = (const float*)d_in[4];
  float* out = (float*)d_out;  // fp32 output (verified R5)

  char* w = (char*)d_ws;
  __hip_bfloat16* WkqvT = (__hip_bfloat16*)(w);            // 3072x1024  (6 MB)
  __hip_bfloat16* WoT = (__hip_bfloat16*)(w + 6291456);    // 1024x1024  (2 MB)
  __hip_bfloat16* Qb = (__hip_bfloat16*)(w + 8388608);     // [B][H][S][64] (8 MB)
  __hip_bfloat16* Kb = (__hip_bfloat16*)(w + 16777216);    // [B][H][S][64] (8 MB)
  __hip_bfloat16* Vt = (__hip_bfloat16*)(w + 25165824);    // [B][H][64][S] (8 MB)
  __hip_bfloat16* SAb = (__hip_bfloat16*)(w + 33554432);   // [B][S][E]     (8 MB)
  __hip_bfloat16* xb = (__hip_bfloat16*)(w + 41943040);    // [B][S][E]     (8 MB)

  cvt_f2b_kernel<<<4096, 256, 0, stream>>>(x, (u16*)xb, 1048576);
  transpose_f2b<<<dim3(6, 32, 16), dim3(32, 8, 1), 0, stream>>>(
      Wkqv, (u16*)WkqvT, 1024, 192);
  transpose_f2b<<<dim3(32, 32, 1), dim3(32, 8, 1), 0, stream>>>(
      Wo, (u16*)WoT, 1024, 1024);
  kqv_gemm<<<dim3(24, 32), 256, 0, stream>>>(xb, WkqvT, bkqv, Qb, Kb, Vt);
  attn_kernel<<<512, 256, 0, stream>>>(Qb, Kb, Vt, SAb);
  out_gemm<<<dim3(8, 32), 256, 0, stream>>>(SAb, WoT, bo, out);
}